// Round 10
// baseline (111.965 us; speedup 1.0000x reference)
//
#include <hip/hip_runtime.h>
#include <math.h>

// StructureLoss: B=32, C=1, H=W=512, 31x31 box filter, pad 15
#define BB 32
#define HH 512
#define WW 512
#define KK 31
#define PP 15
#define HSEG 8                        // rows per block (2 waves x 4 rows)
#define SEGS (HH / HSEG)              // 64
#define NBLOCKS (BB * SEGS)           // 2048
#define NTHREADS 128                  // 2 waves
#define NXCD 8
#define CHUNKX (NBLOCKS / NXCD)       // 256 blocks per XCD (4 images)

#define CROWS 4                       // rows per staging chunk
#define NCH 10                        // chunks cover rows y0-15 .. y0+24 (38 used)

__device__ inline float wave_reduce(float v) {
    #pragma unroll
    for (int off = 32; off > 0; off >>= 1) v += __shfl_down(v, off);
    return v;
}

// 3 transcendentals/px: e=exp(-|x|), r=rcp(1+e) -> sigmoid = r or 1-r,
// log1p(e) = -log(r)
__device__ inline void accum_px(float s, float tg, float x,
                                float& aw, float& ab, float& ai, float& au) {
    const float inv = 1.0f / (float)(KK * KK);
    float pooled = s * inv;
    float weit = fmaf(5.0f, fabsf(pooled - tg), 1.0f);
    float e  = __expf(-fabsf(x));
    float rr = __builtin_amdgcn_rcpf(1.0f + e);
    float bce = fmaxf(x, 0.0f) - x * tg - __logf(rr);
    float p  = (x >= 0.0f) ? rr : (1.0f - rr);
    aw += weit;
    ab = fmaf(weit, bce, ab);
    ai = fmaf(p * tg, weit, ai);
    au = fmaf(p + tg, weit, au);
}

__device__ inline float4 ld4(const float* base, int y, int c) {
    return *(const float4*)(base + (size_t)y * WW + c);
}

// async 16B global->LDS: dest is wave-uniform base + lane*16 (linear),
// src is per-lane. Load results consume ZERO VGPRs -> MLP is set by the
// vmcnt queue, not the 64-VGPR tier (the R0-R9 invariant limiter).
__device__ inline void gll16(const float* g, float* l) {
    __builtin_amdgcn_global_load_lds(
        (const __attribute__((address_space(1))) void*)g,
        (__attribute__((address_space(3))) void*)l, 16, 0, 0);
}

// issue one chunk's 4 gll for this wave (rows 2w, 2w+1 of the chunk).
// Source rows clamped (zero-padding handled by skipping OOB in accum).
__device__ inline void stage_chunk(const float* tb, float* Sbuf,
                                   int y0, int c, int w, int L) {
    #pragma unroll
    for (int rr = 0; rr < 2; ++rr) {
        const int rowc = 2 * w + rr;
        int j = y0 - PP + c * CROWS + rowc;
        j = min(max(j, 0), HH - 1);
        const float* src = tb + (size_t)j * WW + L * 4;   // per-lane
        float* dst = Sbuf + rowc * WW;                    // wave-uniform
        gll16(src,       dst);        // cols   0..255
        gll16(src + 256, dst + 256);  // cols 256..511
    }
}

// accumulate chunk C's rows into the 8 vertical window sums.
// rel = row - y0 (compile-time). Rows rel in [-8,15] are inside ALL 8
// windows -> single 'mid' accumulator; head/tail rows hit a subrange.
template <int C>
__device__ inline void accum_chunk(const float (*Sb)[WW], int cc, int y0,
                                   float4* vacc, float4& mid) {
    #pragma unroll
    for (int r4 = 0; r4 < CROWS; ++r4) {
        const int rel = C * CROWS + r4 - PP;            // compile-time
        if (rel > PP + HSEG - 1) continue;              // pad rows (skip)
        int j = y0 + rel;
        if (j >= 0 && j < HH) {                         // uniform runtime
            float4 u = *(const float4*)&Sb[r4][cc];
            if (rel >= -8 && rel <= PP) {
                mid.x += u.x; mid.y += u.y; mid.z += u.z; mid.w += u.w;
            } else {
                #pragma unroll
                for (int r = 0; r < HSEG; ++r) {
                    if (r >= rel - PP && r <= rel + PP) {   // compile-time
                        vacc[r].x += u.x; vacc[r].y += u.y;
                        vacc[r].z += u.z; vacc[r].w += u.w;
                    }
                }
            }
        }
    }
}

__global__ __launch_bounds__(NTHREADS) void structure_loss_main(
    const float* __restrict__ pred, const float* __restrict__ target,
    float* __restrict__ partials /* [NBLOCKS][4] */)
{
    __shared__ float S[2][CROWS][WW];   // staging double-buffer, 16 KB
    __shared__ float V[HSEG][WW];       // vertical 31-row sums,   16 KB
    __shared__ float red[2 * 4];

    const int t = threadIdx.x;
    const int w = t >> 6;               // wave 0..1
    const int L = t & 63;               // lane

    // XCD-bijective swizzle: XCD x gets 4 contiguous images.
    const int bid     = blockIdx.x;
    const int logical = (bid & (NXCD - 1)) * CHUNKX + (bid >> 3);
    const int b   = logical >> 6;            // image
    const int seg = logical & (SEGS - 1);    // 8-row segment
    const int y0  = seg * HSEG;

    const float* tb = target + (size_t)b * HH * WW;
    const float* pb = pred   + (size_t)b * HH * WW;

    const int cc = 4 * t;               // accumulate: thread owns 4 cols

    // ---- phase 1: async-staged vertical sums (T3/T4: counted vmcnt,
    // never 0 in the loop; raw s_barrier; sched_barrier fences rule-18).
    stage_chunk(tb, &S[0][0][0], y0, 0, w, L);   // 4 gll/wave
    stage_chunk(tb, &S[1][0][0], y0, 1, w, L);   // 8 outstanding/wave

    float4 vacc[HSEG];
    #pragma unroll
    for (int r = 0; r < HSEG; ++r) vacc[r] = make_float4(0.f, 0.f, 0.f, 0.f);
    float4 mid = make_float4(0.f, 0.f, 0.f, 0.f);

#define CHUNK_STEP(c, WAITSTR)                                              \
    asm volatile("s_waitcnt " WAITSTR ::: "memory");  /* chunk c arrived */ \
    __builtin_amdgcn_sched_barrier(0);                                      \
    __builtin_amdgcn_s_barrier();     /* both waves' halves visible */      \
    accum_chunk<c>(S[(c) & 1], cc, y0, vacc, mid);                          \
    if ((c) + 2 < NCH) {                                                    \
        __builtin_amdgcn_sched_barrier(0);                                  \
        __builtin_amdgcn_s_barrier(); /* both waves done reading buf */     \
        stage_chunk(tb, &S[(c) & 1][0][0], y0, (c) + 2, w, L);              \
    }

    CHUNK_STEP(0, "vmcnt(4)")
    CHUNK_STEP(1, "vmcnt(4)")
    CHUNK_STEP(2, "vmcnt(4)")
    CHUNK_STEP(3, "vmcnt(4)")
    CHUNK_STEP(4, "vmcnt(4)")
    CHUNK_STEP(5, "vmcnt(4)")
    CHUNK_STEP(6, "vmcnt(4)")
    CHUNK_STEP(7, "vmcnt(4)")
    CHUNK_STEP(8, "vmcnt(4)")
    CHUNK_STEP(9, "vmcnt(0)")
#undef CHUNK_STEP

    // fold mid into all 8 windows, publish V
    #pragma unroll
    for (int r = 0; r < HSEG; ++r) {
        float4 v = vacc[r];
        v.x += mid.x; v.y += mid.y; v.z += mid.z; v.w += mid.w;
        *(float4*)&V[r][cc] = v;
    }

    __syncthreads();                    // V complete (full drain, once)

    // ---- phase 2: wave w owns rows y0+4w..y0+4w+3; lane owns [8L,8L+8)
    const int c0 = 8 * L;
    const int yA = y0 + 4 * w;

    const float m_u1 = (L >= 1) ? 1.f : 0.f;
    const float m_u2 = (L >= 2) ? 1.f : 0.f;
    const float m_d1 = (L <= 62) ? 1.f : 0.f;
    const float m_d2 = (L <= 61) ? 1.f : 0.f;

    float aw = 0.f, ab = 0.f, ai = 0.f, au = 0.f;

    #pragma unroll
    for (int r = 0; r < 4; ++r) {
        const int y    = yA + r;
        const int vrow = 4 * w + r;
        float4 tgA = ld4(tb, y, c0), tgB = ld4(tb, y, c0 + 4);  // L2-hot
        float4 prA = ld4(pb, y, c0), prB = ld4(pb, y, c0 + 4);
        float4 vA = *(const float4*)&V[vrow][c0];
        float4 vB = *(const float4*)&V[vrow][c0 + 4];

        // ---- horizontal 31-window via cross-lane (17 shuffles) ----
        float own  = vA.x + vA.y + vA.z + vA.w + vB.x + vB.y + vB.z + vB.w;
        float own7 = own - vA.x;
        float s0 = own
                 + m_u2 * __shfl_up(own7, 2)
                 + m_u1 * __shfl_up(own, 1)
                 + m_d1 * __shfl_down(own, 1);
        float a0 = m_d2 * __shfl_down(vA.x, 2);
        float a1 = m_d2 * __shfl_down(vA.y, 2);
        float a2 = m_d2 * __shfl_down(vA.z, 2);
        float a3 = m_d2 * __shfl_down(vA.w, 2);
        float a4 = m_d2 * __shfl_down(vB.x, 2);
        float a5 = m_d2 * __shfl_down(vB.y, 2);
        float a6 = m_d2 * __shfl_down(vB.z, 2);
        float q0 = m_u2 * __shfl_up(vA.y, 2);
        float q1 = m_u2 * __shfl_up(vA.z, 2);
        float q2 = m_u2 * __shfl_up(vA.w, 2);
        float q3 = m_u2 * __shfl_up(vB.x, 2);
        float q4 = m_u2 * __shfl_up(vB.y, 2);
        float q5 = m_u2 * __shfl_up(vB.z, 2);
        float q6 = m_u2 * __shfl_up(vB.w, 2);

        float s1 = s0 + a0 - q0;
        float s2 = s1 + a1 - q1;
        float s3 = s2 + a2 - q2;
        float s4 = s3 + a3 - q3;
        float s5 = s4 + a4 - q4;
        float s6 = s5 + a5 - q5;
        float s7 = s6 + a6 - q6;

        accum_px(s0, tgA.x, prA.x, aw, ab, ai, au);
        accum_px(s1, tgA.y, prA.y, aw, ab, ai, au);
        accum_px(s2, tgA.z, prA.z, aw, ab, ai, au);
        accum_px(s3, tgA.w, prA.w, aw, ab, ai, au);
        accum_px(s4, tgB.x, prB.x, aw, ab, ai, au);
        accum_px(s5, tgB.y, prB.y, aw, ab, ai, au);
        accum_px(s6, tgB.z, prB.z, aw, ab, ai, au);
        accum_px(s7, tgB.w, prB.w, aw, ab, ai, au);
    }

    // block reduction
    aw = wave_reduce(aw);
    ab = wave_reduce(ab);
    ai = wave_reduce(ai);
    au = wave_reduce(au);
    if (L == 0) {
        red[w * 4 + 0] = aw;
        red[w * 4 + 1] = ab;
        red[w * 4 + 2] = ai;
        red[w * 4 + 3] = au;
    }
    __syncthreads();
    if (t == 0) {
        float ww = 0.f, bc = 0.f, in = 0.f, un = 0.f;
        #pragma unroll
        for (int i = 0; i < 2; ++i) {
            ww += red[i * 4 + 0];
            bc += red[i * 4 + 1];
            in += red[i * 4 + 2];
            un += red[i * 4 + 3];
        }
        float* o = partials + (size_t)logical * 4;
        o[0] = ww; o[1] = bc; o[2] = in; o[3] = un;
    }
}

__global__ __launch_bounds__(256) void structure_loss_finalize(
    const float* __restrict__ partials, float* __restrict__ out)
{
    // partials: [2048][4]; image b owns entries [b*64, (b+1)*64)
    const int t  = threadIdx.x;      // 256 threads
    const int b  = t >> 3;           // image 0..31  (8 threads per image)
    const int i0 = (t & 7) * 8;      // 8 partial-entries per thread
    float w = 0.f, bc = 0.f, in = 0.f, un = 0.f;
    #pragma unroll
    for (int k = 0; k < 8; ++k) {
        float4 v = *(const float4*)(partials + ((size_t)(b * 64 + i0 + k)) * 4);
        w += v.x; bc += v.y; in += v.z; un += v.w;
    }
    #pragma unroll
    for (int off = 4; off > 0; off >>= 1) {
        w  += __shfl_down(w, off);
        bc += __shfl_down(bc, off);
        in += __shfl_down(in, off);
        un += __shfl_down(un, off);
    }
    __shared__ float vals[32];
    if ((t & 7) == 0) {
        float wbce = bc / w;
        float wiou = 1.0f - (in + 1.0f) / (un - in + 1.0f);
        vals[b] = wbce + wiou;
    }
    __syncthreads();
    if (t < 64) {
        float v = (t < 32) ? vals[t] : 0.0f;
        v = wave_reduce(v);
        if (t == 0) out[0] = v / (float)BB;
    }
}

extern "C" void kernel_launch(void* const* d_in, const int* in_sizes, int n_in,
                              void* d_out, int out_size, void* d_ws, size_t ws_size,
                              hipStream_t stream) {
    const float* pred   = (const float*)d_in[0];
    const float* target = (const float*)d_in[1];
    float* out      = (float*)d_out;
    float* partials = (float*)d_ws;   // NBLOCKS*4 floats = 32 KB

    structure_loss_main<<<NBLOCKS, NTHREADS, 0, stream>>>(pred, target, partials);
    structure_loss_finalize<<<1, 256, 0, stream>>>(partials, out);
}

// Round 11
// 110.154 us; speedup vs baseline: 1.0164x; 1.0164x over previous
//
#include <hip/hip_runtime.h>
#include <math.h>

// StructureLoss: B=32, C=1, H=W=512, 31x31 box filter, pad 15
#define BB 32
#define HH 512
#define WW 512
#define KK 31
#define PP 15
#define HSEG 8                        // rows per block (4 waves x 2 rows)
#define SEGS (HH / HSEG)              // 64
#define NBLOCKS (BB * SEGS)           // 2048
#define NTHREADS 256                  // 4 waves
#define NXCD 8
#define CHUNKX (NBLOCKS / NXCD)       // 256 blocks per XCD (4 images)
#define SROWS 19                      // rows per staging burst

__device__ inline float wave_reduce(float v) {
    #pragma unroll
    for (int off = 32; off > 0; off >>= 1) v += __shfl_down(v, off);
    return v;
}

// 3 transcendentals/px: e=exp(-|x|), r=rcp(1+e) -> sigmoid = r or 1-r,
// log1p(e) = -log(r)
__device__ inline void accum_px(float s, float tg, float x,
                                float& aw, float& ab, float& ai, float& au) {
    const float inv = 1.0f / (float)(KK * KK);
    float pooled = s * inv;
    float weit = fmaf(5.0f, fabsf(pooled - tg), 1.0f);
    float e  = __expf(-fabsf(x));
    float rr = __builtin_amdgcn_rcpf(1.0f + e);
    float bce = fmaxf(x, 0.0f) - x * tg - __logf(rr);
    float p  = (x >= 0.0f) ? rr : (1.0f - rr);
    aw += weit;
    ab = fmaf(weit, bce, ab);
    ai = fmaf(p * tg, weit, ai);
    au = fmaf(p + tg, weit, au);
}

__device__ inline float4 ld4(const float* base, int y, int c) {
    return *(const float4*)(base + (size_t)y * WW + c);
}

// async 16B global->LDS: dest = wave-uniform base + lane*16 (linear),
// src per-lane. Zero VGPR destination -> burst depth is NOT capped by the
// 64-VGPR register-recycling waits that chopped every register-load
// variant (R0-R9) into ~3KB/CU of in-flight bytes.
__device__ inline void gll16(const float* g, float* l) {
    __builtin_amdgcn_global_load_lds(
        (const __attribute__((address_space(1))) void*)g,
        (__attribute__((address_space(3))) void*)l, 16, 0, 0);
}

// stage 19 target rows (abs rows y0+relbase .. +18) into Sb[0..18].
// wave w owns slots s = w, w+4, ... ; 2 gll per row (cols 0-255, 256-511).
// OOB rows source-clamped; their contribution is skipped in accum.
__device__ inline void stage19(const float* tb, float (*Sb)[WW],
                               int y0, int relbase, int w, int L) {
    #pragma unroll
    for (int k = 0; k < 5; ++k) {
        int s = 4 * k + w;
        if (s < SROWS) {
            int j = min(max(y0 + relbase + s, 0), HH - 1);
            const float* src = tb + (size_t)j * WW + L * 4;
            gll16(src,       &Sb[s][0]);
            gll16(src + 256, &Sb[s][256]);
        }
    }
}

__global__ __launch_bounds__(NTHREADS) void structure_loss_main(
    const float* __restrict__ pred, const float* __restrict__ target,
    float* __restrict__ partials /* [NBLOCKS][4] */)
{
    __shared__ float S[SROWS][WW];    // staging burst + (later) V, 38 KB
    __shared__ float P[HSEG][WW];     // staged pred rows,          16 KB
    __shared__ float red[4 * 4];

    const int t = threadIdx.x;
    const int w = t >> 6;             // wave 0..3
    const int L = t & 63;             // lane

    // XCD-bijective swizzle: XCD x gets 4 contiguous images.
    const int bid     = blockIdx.x;
    const int logical = (bid & (NXCD - 1)) * CHUNKX + (bid >> 3);
    const int b   = logical >> 6;          // image
    const int seg = logical & (SEGS - 1);  // 8-row segment
    const int y0  = seg * HSEG;

    const float* tb = target + (size_t)b * HH * WW;
    const float* pb = pred   + (size_t)b * HH * WW;

    // ---- burst 1: 14 gll/wave back-to-back, zero waits between -----------
    stage19(tb, S, y0, -PP, w, L);    // target rows rel -15..3  (10 gll)
    {                                 // pred rows y0..y0+7       (4 gll)
        #pragma unroll
        for (int rr = 0; rr < 2; ++rr) {
            int r = 2 * w + rr;
            const float* src = pb + (size_t)(y0 + r) * WW + L * 4;
            gll16(src,       &P[r][0]);
            gll16(src + 256, &P[r][256]);
        }
    }
    __syncthreads();                  // single full drain + barrier

    // ---- accum A: thread owns cols c, c+1 (float2) ------------------------
    const int c = 2 * t;
    float2 vacc[HSEG];
    #pragma unroll
    for (int r = 0; r < HSEG; ++r) vacc[r] = make_float2(0.f, 0.f);
    float2 mid = make_float2(0.f, 0.f);

    #pragma unroll
    for (int s = 0; s < SROWS; ++s) {
        const int rel = s - PP;                 // -15..3 (compile-time)
        if (y0 + rel >= 0) {                    // block-uniform skip (pad)
            float2 u = *(const float2*)&S[s][c];
            if (rel >= -8) { mid.x += u.x; mid.y += u.y; }
            else {
                #pragma unroll
                for (int r = 0; r < HSEG; ++r)
                    if (r <= rel + PP) { vacc[r].x += u.x; vacc[r].y += u.y; }
            }
        }
    }
    __syncthreads();                  // all reads of S done -> reuse buffer

    // ---- burst 2: target rows rel 4..22 (10 gll/wave) ---------------------
    stage19(tb, S, y0, 4, w, L);
    __syncthreads();                  // drain

    #pragma unroll
    for (int s = 0; s < SROWS; ++s) {
        const int rel = s + 4;                  // 4..22 (compile-time)
        if (y0 + rel < HH) {                    // block-uniform skip (pad)
            float2 u = *(const float2*)&S[s][c];
            if (rel <= PP) { mid.x += u.x; mid.y += u.y; }
            else {
                #pragma unroll
                for (int r = 0; r < HSEG; ++r)
                    if (r >= rel - PP) { vacc[r].x += u.x; vacc[r].y += u.y; }
            }
        }
    }
    // publish V into the dead staging buffer (own columns only -> race-free)
    #pragma unroll
    for (int r = 0; r < HSEG; ++r) {
        float2 v = make_float2(vacc[r].x + mid.x, vacc[r].y + mid.y);
        *(float2*)&S[r][c] = v;
    }
    __syncthreads();                  // V complete

    // ---- phase 2: wave w owns rows y0+2w, y0+2w+1; lane owns [8L,8L+8) ----
    const int c0 = 8 * L;
    const int yA = y0 + 2 * w;

    const float m_u1 = (L >= 1) ? 1.f : 0.f;
    const float m_u2 = (L >= 2) ? 1.f : 0.f;
    const float m_d1 = (L <= 62) ? 1.f : 0.f;
    const float m_d2 = (L <= 61) ? 1.f : 0.f;

    float aw = 0.f, ab = 0.f, ai = 0.f, au = 0.f;

    #pragma unroll
    for (int r = 0; r < 2; ++r) {
        const int y    = yA + r;
        const int vrow = 2 * w + r;
        float4 tgA = ld4(tb, y, c0), tgB = ld4(tb, y, c0 + 4);  // L2-hot
        float4 prA = *(const float4*)&P[vrow][c0];              // staged
        float4 prB = *(const float4*)&P[vrow][c0 + 4];
        float4 vA  = *(const float4*)&S[vrow][c0];
        float4 vB  = *(const float4*)&S[vrow][c0 + 4];

        // ---- horizontal 31-window via cross-lane (17 shuffles) ----
        float own  = vA.x + vA.y + vA.z + vA.w + vB.x + vB.y + vB.z + vB.w;
        float own7 = own - vA.x;
        float s0 = own
                 + m_u2 * __shfl_up(own7, 2)
                 + m_u1 * __shfl_up(own, 1)
                 + m_d1 * __shfl_down(own, 1);
        float a0 = m_d2 * __shfl_down(vA.x, 2);
        float a1 = m_d2 * __shfl_down(vA.y, 2);
        float a2 = m_d2 * __shfl_down(vA.z, 2);
        float a3 = m_d2 * __shfl_down(vA.w, 2);
        float a4 = m_d2 * __shfl_down(vB.x, 2);
        float a5 = m_d2 * __shfl_down(vB.y, 2);
        float a6 = m_d2 * __shfl_down(vB.z, 2);
        float q0 = m_u2 * __shfl_up(vA.y, 2);
        float q1 = m_u2 * __shfl_up(vA.z, 2);
        float q2 = m_u2 * __shfl_up(vA.w, 2);
        float q3 = m_u2 * __shfl_up(vB.x, 2);
        float q4 = m_u2 * __shfl_up(vB.y, 2);
        float q5 = m_u2 * __shfl_up(vB.z, 2);
        float q6 = m_u2 * __shfl_up(vB.w, 2);

        float s1 = s0 + a0 - q0;
        float s2 = s1 + a1 - q1;
        float s3 = s2 + a2 - q2;
        float s4 = s3 + a3 - q3;
        float s5 = s4 + a4 - q4;
        float s6 = s5 + a5 - q5;
        float s7 = s6 + a6 - q6;

        accum_px(s0, tgA.x, prA.x, aw, ab, ai, au);
        accum_px(s1, tgA.y, prA.y, aw, ab, ai, au);
        accum_px(s2, tgA.z, prA.z, aw, ab, ai, au);
        accum_px(s3, tgA.w, prA.w, aw, ab, ai, au);
        accum_px(s4, tgB.x, prB.x, aw, ab, ai, au);
        accum_px(s5, tgB.y, prB.y, aw, ab, ai, au);
        accum_px(s6, tgB.z, prB.z, aw, ab, ai, au);
        accum_px(s7, tgB.w, prB.w, aw, ab, ai, au);
    }

    // block reduction
    aw = wave_reduce(aw);
    ab = wave_reduce(ab);
    ai = wave_reduce(ai);
    au = wave_reduce(au);
    if (L == 0) {
        red[w * 4 + 0] = aw;
        red[w * 4 + 1] = ab;
        red[w * 4 + 2] = ai;
        red[w * 4 + 3] = au;
    }
    __syncthreads();
    if (t == 0) {
        float ww = 0.f, bc = 0.f, in = 0.f, un = 0.f;
        #pragma unroll
        for (int i = 0; i < 4; ++i) {
            ww += red[i * 4 + 0];
            bc += red[i * 4 + 1];
            in += red[i * 4 + 2];
            un += red[i * 4 + 3];
        }
        float* o = partials + (size_t)logical * 4;
        o[0] = ww; o[1] = bc; o[2] = in; o[3] = un;
    }
}

__global__ __launch_bounds__(256) void structure_loss_finalize(
    const float* __restrict__ partials, float* __restrict__ out)
{
    // partials: [2048][4]; image b owns entries [b*64, (b+1)*64)
    const int t  = threadIdx.x;      // 256 threads
    const int b  = t >> 3;           // image 0..31  (8 threads per image)
    const int i0 = (t & 7) * 8;      // 8 partial-entries per thread
    float w = 0.f, bc = 0.f, in = 0.f, un = 0.f;
    #pragma unroll
    for (int k = 0; k < 8; ++k) {
        float4 v = *(const float4*)(partials + ((size_t)(b * 64 + i0 + k)) * 4);
        w += v.x; bc += v.y; in += v.z; un += v.w;
    }
    #pragma unroll
    for (int off = 4; off > 0; off >>= 1) {
        w  += __shfl_down(w, off);
        bc += __shfl_down(bc, off);
        in += __shfl_down(in, off);
        un += __shfl_down(un, off);
    }
    __shared__ float vals[32];
    if ((t & 7) == 0) {
        float wbce = bc / w;
        float wiou = 1.0f - (in + 1.0f) / (un - in + 1.0f);
        vals[b] = wbce + wiou;
    }
    __syncthreads();
    if (t < 64) {
        float v = (t < 32) ? vals[t] : 0.0f;
        v = wave_reduce(v);
        if (t == 0) out[0] = v / (float)BB;
    }
}

extern "C" void kernel_launch(void* const* d_in, const int* in_sizes, int n_in,
                              void* d_out, int out_size, void* d_ws, size_t ws_size,
                              hipStream_t stream) {
    const float* pred   = (const float*)d_in[0];
    const float* target = (const float*)d_in[1];
    float* out      = (float*)d_out;
    float* partials = (float*)d_ws;   // NBLOCKS*4 floats = 32 KB

    structure_loss_main<<<NBLOCKS, NTHREADS, 0, stream>>>(pred, target, partials);
    structure_loss_finalize<<<1, 256, 0, stream>>>(partials, out);
}

// Round 12
// 106.027 us; speedup vs baseline: 1.0560x; 1.0389x over previous
//
#include <hip/hip_runtime.h>
#include <math.h>

// StructureLoss: B=32, C=1, H=W=512, 31x31 box filter, pad 15
//
// FINAL (R8 config, best verified: total 101.6 us, absmax 0.0).
// Structural analysis (R0-R11): main kernel ~31 us, pinned by the
// per-CU outstanding-line limit on the demand-read path (~128 lines x
// 64 B / 900 ns cold-HBM x 256 CU ~= 2.2 TB/s), with FETCH ~= unique
// input bytes and compute fully hidden. Six orthogonal MLP/occupancy/
// async-staging attacks were all neutral-or-worse; this geometry
// (32 waves/CU, one balanced residency round, no spill) is the floor.
#define BB 32
#define HH 512
#define WW 512
#define KK 31
#define PP 15
#define HSEG 4                        // rows per block (2 waves x 2 rows)
#define SEGS (HH / HSEG)              // 128
#define NBLOCKS (BB * SEGS)           // 4096 -> 16 wg/CU x 2 waves = 32 waves/CU
#define NTHREADS 128
#define NXCD 8
#define CHUNK (NBLOCKS / NXCD)        // 512 blocks per XCD (4 images)

__device__ inline float wave_reduce(float v) {
    #pragma unroll
    for (int off = 32; off > 0; off >>= 1) v += __shfl_down(v, off);
    return v;
}

// 3 transcendentals/px: e=exp(-|x|), r=rcp(1+e) -> sigmoid = r or 1-r,
// log1p(e) = -log(r)
__device__ inline void accum_px(float s, float tg, float x,
                                float& aw, float& ab, float& ai, float& au) {
    const float inv = 1.0f / (float)(KK * KK);
    float pooled = s * inv;
    float weit = fmaf(5.0f, fabsf(pooled - tg), 1.0f);
    float e  = __expf(-fabsf(x));
    float rr = __builtin_amdgcn_rcpf(1.0f + e);
    float bce = fmaxf(x, 0.0f) - x * tg - __logf(rr);
    float p  = (x >= 0.0f) ? rr : (1.0f - rr);
    aw += weit;
    ab = fmaf(weit, bce, ab);
    ai = fmaf(p * tg, weit, ai);
    au = fmaf(p + tg, weit, au);
}

__device__ inline float4 ld4(const float* base, int y, int c) {
    return *(const float4*)(base + (size_t)y * WW + c);
}
// row-clamped float4 load, zeroed if row OOB
__device__ inline float4 ld4z(const float* base, int y, int c) {
    int yc = min(max(y, 0), HH - 1);
    float4 v = *(const float4*)(base + (size_t)yc * WW + c);
    if (y < 0 || y >= HH) v = make_float4(0.f, 0.f, 0.f, 0.f);
    return v;
}

// Live set ~45 regs fits the 64-reg tier spill-free (R1/R4/R5 lesson:
// never force the allocator's budget; shrink the live set instead).
__global__ __launch_bounds__(NTHREADS) void structure_loss_main(
    const float* __restrict__ pred, const float* __restrict__ target,
    float* __restrict__ partials /* [NBLOCKS][4] */)
{
    __shared__ float V[HSEG][WW];     // vertical 31-row sums, 8 KB
    __shared__ float red[2 * 4];

    const int t = threadIdx.x;
    const int w = t >> 6;             // wave 0..1
    const int L = t & 63;             // lane

    // XCD-bijective swizzle: XCD x gets 4 contiguous images -> vertical
    // halos of neighboring segments hit that XCD's L2. 4096 % 8 == 0.
    const int bid     = blockIdx.x;
    const int logical = (bid & (NXCD - 1)) * CHUNK + (bid >> 3);
    const int b   = logical >> 7;          // image   (logical / SEGS)
    const int seg = logical & (SEGS - 1);  // 4-row segment
    const int y0  = seg * HSEG;

    const float* tb = target + (size_t)b * HH * WW;
    const float* pb = pred   + (size_t)b * HH * WW;

    // ---- phase 1: cooperative vertical sums. thread owns cols 4t..4t+3
    // (128 x 4 = 512). Serial slide, ascending 31-row sum for V[0], then
    // slide add/sub for V[1..3] (bit-identical to reduce_window grouping).
    {
        const int c = 4 * t;
        float4 run = make_float4(0.f, 0.f, 0.f, 0.f);
        if (y0 >= PP && y0 + HSEG - 1 + PP < HH) {   // interior (uniform)
            #pragma unroll
            for (int j = -PP; j <= PP; ++j) {
                float4 u = ld4(tb, y0 + j, c);
                run.x += u.x; run.y += u.y; run.z += u.z; run.w += u.w;
            }
            *(float4*)&V[0][c] = run;
            #pragma unroll
            for (int r = 1; r < HSEG; ++r) {
                float4 ad = ld4(tb, y0 + r + PP, c);
                float4 sb = ld4(tb, y0 + r - PP - 1, c);
                run.x += ad.x - sb.x; run.y += ad.y - sb.y;
                run.z += ad.z - sb.z; run.w += ad.w - sb.w;
                *(float4*)&V[r][c] = run;
            }
        } else {
            #pragma unroll
            for (int j = -PP; j <= PP; ++j) {
                float4 u = ld4z(tb, y0 + j, c);
                run.x += u.x; run.y += u.y; run.z += u.z; run.w += u.w;
            }
            *(float4*)&V[0][c] = run;
            #pragma unroll
            for (int r = 1; r < HSEG; ++r) {
                float4 ad = ld4z(tb, y0 + r + PP, c);
                float4 sb = ld4z(tb, y0 + r - PP - 1, c);
                run.x += ad.x - sb.x; run.y += ad.y - sb.y;
                run.z += ad.z - sb.z; run.w += ad.w - sb.w;
                *(float4*)&V[r][c] = run;
            }
        }
    }

    __syncthreads();

    // ---- phase 2: wave w owns rows y0+2w, y0+2w+1; lane owns cols [8L,8L+8)
    const int c0 = 8 * L;
    const int yA = y0 + 2 * w;

    // edge masks for cross-lane halo (exact zero padding at row ends)
    const float m_u1 = (L >= 1) ? 1.f : 0.f;
    const float m_u2 = (L >= 2) ? 1.f : 0.f;
    const float m_d1 = (L <= 62) ? 1.f : 0.f;
    const float m_d2 = (L <= 61) ? 1.f : 0.f;

    float aw = 0.f, ab = 0.f, ai = 0.f, au = 0.f;

    #pragma unroll
    for (int r = 0; r < 2; ++r) {
        const int y    = yA + r;
        const int vrow = 2 * w + r;
        float4 tgA = ld4(tb, y, c0), tgB = ld4(tb, y, c0 + 4);
        float4 prA = ld4(pb, y, c0), prB = ld4(pb, y, c0 + 4);
        float4 vA = *(const float4*)&V[vrow][c0];
        float4 vB = *(const float4*)&V[vrow][c0 + 4];

        // ---- horizontal 31-window via cross-lane (17 shuffles, no LDS) ----
        float own  = vA.x + vA.y + vA.z + vA.w + vB.x + vB.y + vB.z + vB.w;
        float own7 = own - vA.x;   // neighbor's cols 1..7 when shifted
        float s0 = own
                 + m_u2 * __shfl_up(own7, 2)
                 + m_u1 * __shfl_up(own, 1)
                 + m_d1 * __shfl_down(own, 1);
        // add taps: cols c0+16..c0+22 = lane L+2 elems 0..6
        float a0 = m_d2 * __shfl_down(vA.x, 2);
        float a1 = m_d2 * __shfl_down(vA.y, 2);
        float a2 = m_d2 * __shfl_down(vA.z, 2);
        float a3 = m_d2 * __shfl_down(vA.w, 2);
        float a4 = m_d2 * __shfl_down(vB.x, 2);
        float a5 = m_d2 * __shfl_down(vB.y, 2);
        float a6 = m_d2 * __shfl_down(vB.z, 2);
        // sub taps: cols c0-15..c0-9 = lane L-2 elems 1..7
        float q0 = m_u2 * __shfl_up(vA.y, 2);
        float q1 = m_u2 * __shfl_up(vA.z, 2);
        float q2 = m_u2 * __shfl_up(vA.w, 2);
        float q3 = m_u2 * __shfl_up(vB.x, 2);
        float q4 = m_u2 * __shfl_up(vB.y, 2);
        float q5 = m_u2 * __shfl_up(vB.z, 2);
        float q6 = m_u2 * __shfl_up(vB.w, 2);

        float s1 = s0 + a0 - q0;
        float s2 = s1 + a1 - q1;
        float s3 = s2 + a2 - q2;
        float s4 = s3 + a3 - q3;
        float s5 = s4 + a4 - q4;
        float s6 = s5 + a5 - q5;
        float s7 = s6 + a6 - q6;

        accum_px(s0, tgA.x, prA.x, aw, ab, ai, au);
        accum_px(s1, tgA.y, prA.y, aw, ab, ai, au);
        accum_px(s2, tgA.z, prA.z, aw, ab, ai, au);
        accum_px(s3, tgA.w, prA.w, aw, ab, ai, au);
        accum_px(s4, tgB.x, prB.x, aw, ab, ai, au);
        accum_px(s5, tgB.y, prB.y, aw, ab, ai, au);
        accum_px(s6, tgB.z, prB.z, aw, ab, ai, au);
        accum_px(s7, tgB.w, prB.w, aw, ab, ai, au);
    }

    // block reduction (single barrier pair at the very end)
    aw = wave_reduce(aw);
    ab = wave_reduce(ab);
    ai = wave_reduce(ai);
    au = wave_reduce(au);
    if (L == 0) {
        red[w * 4 + 0] = aw;
        red[w * 4 + 1] = ab;
        red[w * 4 + 2] = ai;
        red[w * 4 + 3] = au;
    }
    __syncthreads();
    if (t == 0) {
        float ww = 0.f, bc = 0.f, in = 0.f, un = 0.f;
        #pragma unroll
        for (int i = 0; i < 2; ++i) {
            ww += red[i * 4 + 0];
            bc += red[i * 4 + 1];
            in += red[i * 4 + 2];
            un += red[i * 4 + 3];
        }
        float* o = partials + (size_t)logical * 4;
        o[0] = ww; o[1] = bc; o[2] = in; o[3] = un;
    }
}

__global__ __launch_bounds__(256) void structure_loss_finalize(
    const float* __restrict__ partials, float* __restrict__ out)
{
    // partials: [4096][4]; image b owns entries [b*128, (b+1)*128)
    const int t  = threadIdx.x;      // 256 threads
    const int b  = t >> 3;           // image 0..31  (8 threads per image)
    const int i0 = (t & 7) * 16;     // 16 partial-entries per thread
    float w = 0.f, bc = 0.f, in = 0.f, un = 0.f;
    #pragma unroll
    for (int k = 0; k < 16; ++k) {
        float4 v = *(const float4*)(partials + ((size_t)(b * 128 + i0 + k)) * 4);
        w += v.x; bc += v.y; in += v.z; un += v.w;
    }
    #pragma unroll
    for (int off = 4; off > 0; off >>= 1) {
        w  += __shfl_down(w, off);
        bc += __shfl_down(bc, off);
        in += __shfl_down(in, off);
        un += __shfl_down(un, off);
    }
    __shared__ float vals[32];
    if ((t & 7) == 0) {
        float wbce = bc / w;
        float wiou = 1.0f - (in + 1.0f) / (un - in + 1.0f);
        vals[b] = wbce + wiou;
    }
    __syncthreads();
    if (t < 64) {
        float v = (t < 32) ? vals[t] : 0.0f;
        v = wave_reduce(v);
        if (t == 0) out[0] = v / (float)BB;
    }
}

extern "C" void kernel_launch(void* const* d_in, const int* in_sizes, int n_in,
                              void* d_out, int out_size, void* d_ws, size_t ws_size,
                              hipStream_t stream) {
    const float* pred   = (const float*)d_in[0];
    const float* target = (const float*)d_in[1];
    float* out      = (float*)d_out;
    float* partials = (float*)d_ws;   // NBLOCKS*4 floats = 64 KB

    structure_loss_main<<<NBLOCKS, NTHREADS, 0, stream>>>(pred, target, partials);
    structure_loss_finalize<<<1, 256, 0, stream>>>(partials, out);
}